// Round 7
// baseline (316.032 us; speedup 1.0000x reference)
//
#include <hip/hip_runtime.h>
#include <hip/hip_fp16.h>
#include <math.h>

#define NN 100000
#define NE 1200000
#define INC 128
#define HIDC 64
#define EPSV 1e-5f
#define NPB 1024                               // nodes per bucket
#define NBUCK ((NN + NPB - 1) / NPB)           // 98
#define CHUNK 8192                             // edges per partA/hist block

typedef float f4 __attribute__((ext_vector_type(4)));
typedef _Float16 hf;
typedef _Float16 h4 __attribute__((ext_vector_type(4)));
typedef unsigned long long u64;

// ---- bucket histogram ----
__global__ __launch_bounds__(256) void k_hist(const int* __restrict__ dst, int* bucketTotal) {
    __shared__ int hist[NBUCK];
    int t = threadIdx.x;
    if (t < NBUCK) hist[t] = 0;
    __syncthreads();
    int e0 = blockIdx.x * CHUNK;
#pragma unroll
    for (int j = 0; j < CHUNK / 256; ++j) {
        int e = e0 + j * 256 + t;
        if (e < NE) atomicAdd(&hist[dst[e] >> 10], 1);
    }
    __syncthreads();
    if (t < NBUCK && hist[t]) atomicAdd(&bucketTotal[t], hist[t]);
}

// ---- scan bucket totals ----
__global__ void k_bscan(const int* __restrict__ bucketTotal,
                        int* bucketStart, int* bucketCur, int* cursor) {
    __shared__ int s[NBUCK];
    int t = threadIdx.x;
    if (t < NBUCK) s[t] = bucketTotal[t];
    __syncthreads();
    if (t == 0) {
        int acc = 0;
        for (int i = 0; i < NBUCK; ++i) { int v = s[i]; s[i] = acc; acc += v; }
    }
    __syncthreads();
    if (t < NBUCK) { bucketStart[t] = s[t]; bucketCur[t] = s[t]; }
    if (t == 0) { bucketStart[NBUCK] = NE; cursor[NN] = NE; }
}

// ---- pass A: partition (src,dst) pairs into bucket regions ----
__global__ __launch_bounds__(256) void k_partA(
    const int* __restrict__ src, const int* __restrict__ dst,
    int* bucketCur, u64* __restrict__ pairs) {
    __shared__ int hist[NBUCK], base[NBUCK];
    int t = threadIdx.x;
    if (t < NBUCK) hist[t] = 0;
    __syncthreads();
    int e0 = blockIdx.x * CHUNK;
    int dloc[32];
#pragma unroll
    for (int j = 0; j < 32; ++j) {
        int e = e0 + j * 256 + t;
        int d = (e < NE) ? dst[e] : -1;
        dloc[j] = d;
        if (d >= 0) atomicAdd(&hist[d >> 10], 1);
    }
    __syncthreads();
    if (t < NBUCK) base[t] = atomicAdd(&bucketCur[t], hist[t]);
    __syncthreads();
    if (t < NBUCK) hist[t] = 0;
    __syncthreads();
#pragma unroll
    for (int j = 0; j < 32; ++j) {
        int e = e0 + j * 256 + t;
        int d = dloc[j];
        if (d >= 0) {
            int b = d >> 10;
            int pos = base[b] + atomicAdd(&hist[b], 1);
            pairs[pos] = ((u64)(unsigned)d << 32) | (unsigned)src[e];
        }
    }
}

// ---- pass B: per-bucket counts -> cursor/dinv; local scatter ----
__global__ __launch_bounds__(256) void k_partB(
    const int* __restrict__ bucketStart, const u64* __restrict__ pairs,
    int* __restrict__ srcSorted, int* __restrict__ cursor, float* __restrict__ dinv) {
    __shared__ int cnt1024[NPB];
    __shared__ int off1024[NPB];
    __shared__ int part[256];
    int b = blockIdx.x, t = threadIdx.x;
    int nbase = b * NPB;
    int beg = bucketStart[b], end = bucketStart[b + 1];
    for (int i = t; i < NPB; i += 256) cnt1024[i] = 0;
    __syncthreads();
    for (int i = beg + t; i < end; i += 256)
        atomicAdd(&cnt1024[(int)(pairs[i] >> 32) - nbase], 1);
    __syncthreads();
    int c[4]; int s = 0;
#pragma unroll
    for (int j = 0; j < 4; ++j) { c[j] = cnt1024[t * 4 + j]; s += c[j]; }
    part[t] = s;
    __syncthreads();
    for (int off = 1; off < 256; off <<= 1) {
        int x = (t >= off) ? part[t - off] : 0;
        __syncthreads();
        part[t] += x;
        __syncthreads();
    }
    int run = part[t] - s;
#pragma unroll
    for (int j = 0; j < 4; ++j) {
        int node = nbase + t * 4 + j;
        if (node < NN) {
            cursor[node] = beg + run;
            off1024[t * 4 + j] = run;
            dinv[node] = rsqrtf((float)c[j] + 1.0f);
            run += c[j];
        }
    }
    __syncthreads();
    for (int i = beg + t; i < end; i += 256) {
        u64 p = pairs[i];
        int d = (int)(p >> 32);
        int pos = beg + atomicAdd(&off1024[d - nbase], 1);
        srcSorted[pos] = (int)(p & 0xffffffffu);
    }
}

// ---------------- layer-1 GEMM: hp[n] = fp16( dinv[n] * (x[n] @ W1) ) ----------------
// fp16 LDS tiles (xs 16KB + wsh 8KB = 24KB), fp32 accumulate.
// skew s(r) = ((r>>2)*4): within a wave instruction the 4 rows accessed have
// distinct (r>>2) -> distinct banks. Conflict-free.
__global__ __launch_bounds__(256) void k_gemm1(
    const float* __restrict__ x, const float* __restrict__ W,
    const float* __restrict__ dinv, hf* __restrict__ hp) {
    __shared__ hf xs[64 * 128];
    __shared__ hf wsh[128 * 64];
    int tid = threadIdx.x;
    int nodeBase = blockIdx.x * 64;
    // stage W (128x64) fp32 -> fp16
    for (int idx = tid; idx < 128 * 64 / 4; idx += 256) {
        f4 w = *(const f4*)&W[idx * 4];
        h4 o;
#pragma unroll
        for (int j = 0; j < 4; ++j) o[j] = (hf)w[j];
        *(h4*)&wsh[idx * 4] = o;
    }
    // stage x tile (64x128) fp32 -> fp16, skewed
    for (int idx = tid; idx < 64 * 32; idx += 256) {
        int r = idx >> 5, k = (idx & 31) * 4;
        f4 v = {0.f, 0.f, 0.f, 0.f};
        int n = nodeBase + r;
        if (n < NN) v = *(const f4*)&x[(size_t)n * INC + k];
        h4 o;
#pragma unroll
        for (int j = 0; j < 4; ++j) o[j] = (hf)v[j];
        *(h4*)&xs[r * 128 + ((k + ((r >> 2) << 2)) & 127)] = o;
    }
    __syncthreads();
    int cg = tid & 15, ng = tid >> 4;
    int c0 = cg * 4, n0 = ng * 4;
    int skw = (ng << 2);                 // (r>>2)==ng for rows n0..n0+3
    f4 acc0 = {0.f,0.f,0.f,0.f}, acc1 = acc0, acc2 = acc0, acc3 = acc0;
#pragma unroll 2
    for (int k0 = 0; k0 < INC; k0 += 4) {
        int kc = (k0 + skw) & 127;
        h4 xh0 = *(const h4*)&xs[(n0 + 0) * 128 + kc];
        h4 xh1 = *(const h4*)&xs[(n0 + 1) * 128 + kc];
        h4 xh2 = *(const h4*)&xs[(n0 + 2) * 128 + kc];
        h4 xh3 = *(const h4*)&xs[(n0 + 3) * 128 + kc];
#pragma unroll
        for (int kk = 0; kk < 4; ++kk) {
            h4 wh = *(const h4*)&wsh[(k0 + kk) * 64 + c0];
            f4 wv;
#pragma unroll
            for (int j = 0; j < 4; ++j) wv[j] = (float)wh[j];
            acc0 += (float)xh0[kk] * wv;
            acc1 += (float)xh1[kk] * wv;
            acc2 += (float)xh2[kk] * wv;
            acc3 += (float)xh3[kk] * wv;
        }
    }
    int n = nodeBase + n0;
#pragma unroll
    for (int q = 0; q < 4; ++q) {
        int nn = n + q;
        if (nn < NN) {
            f4 a = (q == 0) ? acc0 : (q == 1) ? acc1 : (q == 2) ? acc2 : acc3;
            float d = dinv[nn];
            h4 o;
#pragma unroll
            for (int j = 0; j < 4; ++j) o[j] = (hf)(a[j] * d);
            *(h4*)&hp[(size_t)nn * HIDC + c0] = o;
        }
    }
}

// ---------------- layer-2 GEMM, BN+ReLU fused, fp16 LDS tiles ----------------
__global__ __launch_bounds__(256) void k_gemm2(
    const float* __restrict__ agg, const float* __restrict__ W,
    const float* __restrict__ scale, const float* __restrict__ shift,
    const float* __restrict__ dinv, hf* __restrict__ hp) {
    __shared__ hf xs[64 * 64];
    __shared__ hf wsh[64 * 64];
    int tid = threadIdx.x;
    int nodeBase = blockIdx.x * 64;
    for (int idx = tid; idx < 64 * 64 / 4; idx += 256) {
        f4 w = *(const f4*)&W[idx * 4];
        h4 o;
#pragma unroll
        for (int j = 0; j < 4; ++j) o[j] = (hf)w[j];
        *(h4*)&wsh[idx * 4] = o;
    }
    for (int idx = tid; idx < 64 * 16; idx += 256) {
        int r = idx >> 4, c = (idx & 15) * 4;
        f4 v = {0.f, 0.f, 0.f, 0.f};
        int n = nodeBase + r;
        if (n < NN) {
            v = *(const f4*)&agg[(size_t)n * HIDC + c];
            f4 sc = *(const f4*)&scale[c];
            f4 sh = *(const f4*)&shift[c];
            v = v * sc + sh;
#pragma unroll
            for (int j = 0; j < 4; ++j) v[j] = fmaxf(v[j], 0.f);
        }
        h4 o;
#pragma unroll
        for (int j = 0; j < 4; ++j) o[j] = (hf)v[j];
        *(h4*)&xs[r * 64 + ((c + ((r >> 2) << 2)) & 63)] = o;
    }
    __syncthreads();
    int cg = tid & 15, ng = tid >> 4;
    int c0 = cg * 4, n0 = ng * 4;
    int skw = (ng << 2);
    f4 acc0 = {0.f,0.f,0.f,0.f}, acc1 = acc0, acc2 = acc0, acc3 = acc0;
#pragma unroll 2
    for (int k0 = 0; k0 < HIDC; k0 += 4) {
        int kc = (k0 + skw) & 63;
        h4 xh0 = *(const h4*)&xs[(n0 + 0) * 64 + kc];
        h4 xh1 = *(const h4*)&xs[(n0 + 1) * 64 + kc];
        h4 xh2 = *(const h4*)&xs[(n0 + 2) * 64 + kc];
        h4 xh3 = *(const h4*)&xs[(n0 + 3) * 64 + kc];
#pragma unroll
        for (int kk = 0; kk < 4; ++kk) {
            h4 wh = *(const h4*)&wsh[(k0 + kk) * 64 + c0];
            f4 wv;
#pragma unroll
            for (int j = 0; j < 4; ++j) wv[j] = (float)wh[j];
            acc0 += (float)xh0[kk] * wv;
            acc1 += (float)xh1[kk] * wv;
            acc2 += (float)xh2[kk] * wv;
            acc3 += (float)xh3[kk] * wv;
        }
    }
    int n = nodeBase + n0;
#pragma unroll
    for (int q = 0; q < 4; ++q) {
        int nn = n + q;
        if (nn < NN) {
            f4 a = (q == 0) ? acc0 : (q == 1) ? acc1 : (q == 2) ? acc2 : acc3;
            float d = dinv[nn];
            h4 o;
#pragma unroll
            for (int j = 0; j < 4; ++j) o[j] = (hf)(a[j] * d);
            *(h4*)&hp[(size_t)nn * HIDC + c0] = o;
        }
    }
}

// ---------------- CSR gather (fp16 table) ----------------
__global__ __launch_bounds__(256) void k_gather(
    const int* __restrict__ cursor, const int* __restrict__ srcSorted,
    const float* __restrict__ dinv, const hf* __restrict__ hp,
    float* __restrict__ agg) {
    int wid = threadIdx.x >> 6, lane = threadIdx.x & 63;
    int n = blockIdx.x * 4 + wid;
    if (n >= NN) return;
    int beg = cursor[n];
    int end = cursor[n + 1];
    float acc = (float)hp[(size_t)n * HIDC + lane];
    for (int base = beg; base < end; base += 64) {
        int m = end - base; if (m > 64) m = 64;
        int si = (base + lane < end) ? srcSorted[base + lane] : 0;
        int j = 0;
        for (; j + 8 <= m; j += 8) {
            int s0 = __shfl(si, j),     s1 = __shfl(si, j + 1);
            int s2 = __shfl(si, j + 2), s3 = __shfl(si, j + 3);
            int s4 = __shfl(si, j + 4), s5 = __shfl(si, j + 5);
            int s6 = __shfl(si, j + 6), s7 = __shfl(si, j + 7);
            float v0 = (float)hp[(size_t)s0 * HIDC + lane];
            float v1 = (float)hp[(size_t)s1 * HIDC + lane];
            float v2 = (float)hp[(size_t)s2 * HIDC + lane];
            float v3 = (float)hp[(size_t)s3 * HIDC + lane];
            float v4 = (float)hp[(size_t)s4 * HIDC + lane];
            float v5 = (float)hp[(size_t)s5 * HIDC + lane];
            float v6 = (float)hp[(size_t)s6 * HIDC + lane];
            float v7 = (float)hp[(size_t)s7 * HIDC + lane];
            acc += ((v0 + v1) + (v2 + v3)) + ((v4 + v5) + (v6 + v7));
        }
        for (; j + 2 <= m; j += 2) {
            int s0 = __shfl(si, j), s1 = __shfl(si, j + 1);
            float v0 = (float)hp[(size_t)s0 * HIDC + lane];
            float v1 = (float)hp[(size_t)s1 * HIDC + lane];
            acc += v0 + v1;
        }
        if (j < m) {
            int s = __shfl(si, j);
            acc += (float)hp[(size_t)s * HIDC + lane];
        }
    }
    agg[(size_t)n * HIDC + lane] = dinv[n] * acc;
}

// ---------------- BN statistics ----------------
__global__ __launch_bounds__(256) void k_stats(
    const float* __restrict__ agg, float* gsum, float* gsq) {
    __shared__ float ls[256], lq[256];
    int tid = threadIdx.x;
    int c = tid & 63, r = tid >> 6;
    float s = 0.0f, q = 0.0f;
    for (int n = blockIdx.x * 4 + r; n < NN; n += gridDim.x * 4) {
        float v = agg[(size_t)n * HIDC + c];
        s += v; q += v * v;
    }
    ls[tid] = s; lq[tid] = q;
    __syncthreads();
    if (tid < 64) {
        s = ls[tid] + ls[tid + 64] + ls[tid + 128] + ls[tid + 192];
        q = lq[tid] + lq[tid + 64] + lq[tid + 128] + lq[tid + 192];
        atomicAdd(&gsum[c], s);
        atomicAdd(&gsq[c], q);
    }
}

__global__ void k_bnfin(const float* __restrict__ gsum, const float* __restrict__ gsq,
                        const float* __restrict__ g, const float* __restrict__ be,
                        float* scale, float* shift) {
    int c = threadIdx.x;
    if (c < HIDC) {
        float mu = gsum[c] * (1.0f / NN);
        float var = gsq[c] * (1.0f / NN) - mu * mu;
        float inv = rsqrtf(var + EPSV);
        float sc = g[c] * inv;
        scale[c] = sc;
        shift[c] = be[c] - mu * sc;
    }
}

// ---------------- MLP head ----------------
__global__ __launch_bounds__(256) void k_mlp(
    const float* __restrict__ agg, const float* __restrict__ scale,
    const float* __restrict__ shift,
    const float* __restrict__ Wm1, const float* __restrict__ bm1,
    const float* __restrict__ Wm2, const float* __restrict__ bm2,
    const float* __restrict__ Wm3, const float* __restrict__ bm3,
    float* __restrict__ out) {
    int n = blockIdx.x * blockDim.x + threadIdx.x;
    if (n >= NN) return;
    float h[HIDC];
#pragma unroll
    for (int c = 0; c < HIDC; ++c)
        h[c] = fmaxf(agg[(size_t)n * HIDC + c] * scale[c] + shift[c], 0.0f);
    float a1[32];
#pragma unroll
    for (int j = 0; j < 32; ++j) {
        float acc = bm1[j];
#pragma unroll
        for (int c = 0; c < HIDC; ++c) acc += h[c] * Wm1[c * 32 + j];
        a1[j] = fmaxf(acc, 0.0f);
    }
    float a2[16];
#pragma unroll
    for (int j = 0; j < 16; ++j) {
        float acc = bm2[j];
#pragma unroll
        for (int c = 0; c < 32; ++c) acc += a1[c] * Wm2[c * 16 + j];
        a2[j] = fmaxf(acc, 0.0f);
    }
    float z = bm3[0];
#pragma unroll
    for (int c = 0; c < 16; ++c) z += a2[c] * Wm3[c];
    out[n] = 1.0f / (1.0f + expf(-z));
}

extern "C" void kernel_launch(void* const* d_in, const int* in_sizes, int n_in,
                              void* d_out, int out_size, void* d_ws, size_t ws_size,
                              hipStream_t stream) {
    const float* x   = (const float*)d_in[0];
    const int*   ei  = (const int*)d_in[1];
    const float* W1  = (const float*)d_in[2];
    // b1 (d_in[3]) cancels in BatchNorm
    const float* g1  = (const float*)d_in[4];
    const float* be1 = (const float*)d_in[5];
    const float* W2  = (const float*)d_in[6];
    // b2 (d_in[7]) cancels in BatchNorm
    const float* g2  = (const float*)d_in[8];
    const float* be2 = (const float*)d_in[9];
    const float* Wm1 = (const float*)d_in[10];
    const float* bm1 = (const float*)d_in[11];
    const float* Wm2 = (const float*)d_in[12];
    const float* bm2 = (const float*)d_in[13];
    const float* Wm3 = (const float*)d_in[14];
    const float* bm3 = (const float*)d_in[15];
    float* out = (float*)d_out;

    const int* srcI = ei;
    const int* dstI = ei + NE;

    int*   bucketTotal = (int*)d_ws;                    // 128
    int*   bucketStart = bucketTotal + 128;             // 128
    int*   bucketCur   = bucketStart + 128;             // 128
    int*   cursor      = bucketCur + 128;               // NN+4
    int*   srcSorted   = cursor + NN + 4;               // NE
    float* dinv        = (float*)(srcSorted + NE);      // NN
    hf*    hp          = (hf*)(dinv + NN);              // NN*64 fp16
    float* bufA        = (float*)(hp + (size_t)NN * HIDC);  // NN*64 fp32
    float* stats       = bufA + (size_t)NN * HIDC;      // 512
    u64*   pairs       = (u64*)hp;                      // aliases hp (dead until gemm1)
    float *sum1 = stats,       *sq1 = stats + 64;
    float *sum2 = stats + 128, *sq2 = stats + 192;
    float *scale1 = stats + 256, *shift1 = stats + 320;
    float *scale2 = stats + 384, *shift2 = stats + 448;

    hipMemsetAsync(bucketTotal, 0, 128 * sizeof(int), stream);
    hipMemsetAsync(stats, 0, 256 * sizeof(float), stream);

    // CSR build
    k_hist<<<(NE + CHUNK - 1) / CHUNK, 256, 0, stream>>>(dstI, bucketTotal);
    k_bscan<<<1, 128, 0, stream>>>(bucketTotal, bucketStart, bucketCur, cursor);
    k_partA<<<(NE + CHUNK - 1) / CHUNK, 256, 0, stream>>>(srcI, dstI, bucketCur, pairs);
    k_partB<<<NBUCK, 256, 0, stream>>>(bucketStart, pairs, srcSorted, cursor, dinv);

    // layer 1
    k_gemm1<<<(NN + 63) / 64, 256, 0, stream>>>(x, W1, dinv, hp);
    k_gather<<<(NN + 3) / 4, 256, 0, stream>>>(cursor, srcSorted, dinv, hp, bufA);
    k_stats<<<512, 256, 0, stream>>>(bufA, sum1, sq1);
    k_bnfin<<<1, 64, 0, stream>>>(sum1, sq1, g1, be1, scale1, shift1);

    // layer 2
    k_gemm2<<<(NN + 63) / 64, 256, 0, stream>>>(bufA, W2, scale1, shift1, dinv, hp);
    k_gather<<<(NN + 3) / 4, 256, 0, stream>>>(cursor, srcSorted, dinv, hp, bufA);
    k_stats<<<512, 256, 0, stream>>>(bufA, sum2, sq2);
    k_bnfin<<<1, 64, 0, stream>>>(sum2, sq2, g2, be2, scale2, shift2);

    // MLP head
    k_mlp<<<(NN + 255) / 256, 256, 0, stream>>>(bufA, scale2, shift2,
                                                Wm1, bm1, Wm2, bm2, Wm3, bm3, out);
}

// Round 8
// 298.642 us; speedup vs baseline: 1.0582x; 1.0582x over previous
//
#include <hip/hip_runtime.h>
#include <hip/hip_fp16.h>
#include <math.h>

#define NN 100000
#define NE 1200000
#define INC 128
#define HIDC 64
#define EPSV 1e-5f
#define NPB 1024                               // nodes per bucket
#define NBUCK ((NN + NPB - 1) / NPB)           // 98
#define CHUNK 8192                             // edges per partA/hist block

typedef float f4 __attribute__((ext_vector_type(4)));
typedef _Float16 hf;
typedef _Float16 h4 __attribute__((ext_vector_type(4)));
typedef _Float16 h8 __attribute__((ext_vector_type(8)));
typedef unsigned long long u64;

// ---- weight prep: transposed fp16 tables W1T[64][128], W2T[64][64] ----
__global__ __launch_bounds__(256) void k_prep(const float* __restrict__ W1,
                                              const float* __restrict__ W2,
                                              hf* __restrict__ w1t, hf* __restrict__ w2t) {
    int t = threadIdx.x;
    for (int i = t; i < 64 * 128; i += 256) {
        int c = i >> 7, k = i & 127;
        w1t[i] = (hf)W1[k * 64 + c];
    }
    for (int i = t; i < 64 * 64; i += 256) {
        int c = i >> 6, k = i & 63;
        w2t[i] = (hf)W2[k * 64 + c];
    }
}

// ---- bucket histogram ----
__global__ __launch_bounds__(256) void k_hist(const int* __restrict__ dst, int* bucketTotal) {
    __shared__ int hist[NBUCK];
    int t = threadIdx.x;
    if (t < NBUCK) hist[t] = 0;
    __syncthreads();
    int e0 = blockIdx.x * CHUNK;
#pragma unroll
    for (int j = 0; j < CHUNK / 256; ++j) {
        int e = e0 + j * 256 + t;
        if (e < NE) atomicAdd(&hist[dst[e] >> 10], 1);
    }
    __syncthreads();
    if (t < NBUCK && hist[t]) atomicAdd(&bucketTotal[t], hist[t]);
}

// ---- scan bucket totals ----
__global__ void k_bscan(const int* __restrict__ bucketTotal,
                        int* bucketStart, int* bucketCur, int* cursor) {
    __shared__ int s[NBUCK];
    int t = threadIdx.x;
    if (t < NBUCK) s[t] = bucketTotal[t];
    __syncthreads();
    if (t == 0) {
        int acc = 0;
        for (int i = 0; i < NBUCK; ++i) { int v = s[i]; s[i] = acc; acc += v; }
    }
    __syncthreads();
    if (t < NBUCK) { bucketStart[t] = s[t]; bucketCur[t] = s[t]; }
    if (t == 0) { bucketStart[NBUCK] = NE; cursor[NN] = NE; }
}

// ---- pass A: partition (src,dst) pairs into bucket regions ----
__global__ __launch_bounds__(256) void k_partA(
    const int* __restrict__ src, const int* __restrict__ dst,
    int* bucketCur, u64* __restrict__ pairs) {
    __shared__ int hist[NBUCK], base[NBUCK];
    int t = threadIdx.x;
    if (t < NBUCK) hist[t] = 0;
    __syncthreads();
    int e0 = blockIdx.x * CHUNK;
    int dloc[32];
#pragma unroll
    for (int j = 0; j < 32; ++j) {
        int e = e0 + j * 256 + t;
        int d = (e < NE) ? dst[e] : -1;
        dloc[j] = d;
        if (d >= 0) atomicAdd(&hist[d >> 10], 1);
    }
    __syncthreads();
    if (t < NBUCK) base[t] = atomicAdd(&bucketCur[t], hist[t]);
    __syncthreads();
    if (t < NBUCK) hist[t] = 0;
    __syncthreads();
#pragma unroll
    for (int j = 0; j < 32; ++j) {
        int e = e0 + j * 256 + t;
        int d = dloc[j];
        if (d >= 0) {
            int b = d >> 10;
            int pos = base[b] + atomicAdd(&hist[b], 1);
            pairs[pos] = ((u64)(unsigned)d << 32) | (unsigned)src[e];
        }
    }
}

// ---- pass B: per-bucket counts -> cursor/dinv; local scatter ----
__global__ __launch_bounds__(256) void k_partB(
    const int* __restrict__ bucketStart, const u64* __restrict__ pairs,
    int* __restrict__ srcSorted, int* __restrict__ cursor, float* __restrict__ dinv) {
    __shared__ int cnt1024[NPB];
    __shared__ int off1024[NPB];
    __shared__ int part[256];
    int b = blockIdx.x, t = threadIdx.x;
    int nbase = b * NPB;
    int beg = bucketStart[b], end = bucketStart[b + 1];
    for (int i = t; i < NPB; i += 256) cnt1024[i] = 0;
    __syncthreads();
    for (int i = beg + t; i < end; i += 256)
        atomicAdd(&cnt1024[(int)(pairs[i] >> 32) - nbase], 1);
    __syncthreads();
    int c[4]; int s = 0;
#pragma unroll
    for (int j = 0; j < 4; ++j) { c[j] = cnt1024[t * 4 + j]; s += c[j]; }
    part[t] = s;
    __syncthreads();
    for (int off = 1; off < 256; off <<= 1) {
        int x = (t >= off) ? part[t - off] : 0;
        __syncthreads();
        part[t] += x;
        __syncthreads();
    }
    int run = part[t] - s;
#pragma unroll
    for (int j = 0; j < 4; ++j) {
        int node = nbase + t * 4 + j;
        if (node < NN) {
            cursor[node] = beg + run;
            off1024[t * 4 + j] = run;
            dinv[node] = rsqrtf((float)c[j] + 1.0f);
            run += c[j];
        }
    }
    __syncthreads();
    for (int i = beg + t; i < end; i += 256) {
        u64 p = pairs[i];
        int d = (int)(p >> 32);
        int pos = beg + atomicAdd(&off1024[d - nbase], 1);
        srcSorted[pos] = (int)(p & 0xffffffffu);
    }
}

// ---------------- layer-1 GEMM via MFMA: hp[n] = fp16(dinv[n] * (x[n] @ W1)) ----------------
// Block = 64 nodes; wave wv owns 16-row tile; no LDS, frags direct from global.
// A-frag: lane l -> row l&15 (of tile), k = (l>>4)*8 + j. B-frag from W1T[c][k].
// C/D: row=(l>>4)*4+reg, col=l&15 (m89-verified mapping).
__global__ __launch_bounds__(256) void k_gemm1(
    const float* __restrict__ x, const hf* __restrict__ w1t,
    const float* __restrict__ dinv, hf* __restrict__ hp) {
    int wv = threadIdx.x >> 6, l = threadIdx.x & 63;
    int r16 = l & 15, kg = l >> 4;
    int nodeBase = blockIdx.x * 64;
    int row = nodeBase + wv * 16 + r16;
    int rowC = row < NN ? row : NN - 1;
    const float* xr = x + (size_t)rowC * INC + kg * 8;
    f4 acc[4] = {{0.f,0.f,0.f,0.f},{0.f,0.f,0.f,0.f},{0.f,0.f,0.f,0.f},{0.f,0.f,0.f,0.f}};
#pragma unroll
    for (int ks = 0; ks < 4; ++ks) {
        f4 alo = *(const f4*)(xr + ks * 32);
        f4 ahi = *(const f4*)(xr + ks * 32 + 4);
        h8 a;
#pragma unroll
        for (int j = 0; j < 4; ++j) { a[j] = (hf)alo[j]; a[4 + j] = (hf)ahi[j]; }
#pragma unroll
        for (int n = 0; n < 4; ++n) {
            h8 b = *(const h8*)(w1t + (n * 16 + r16) * INC + ks * 32 + kg * 8);
            acc[n] = __builtin_amdgcn_mfma_f32_16x16x32_f16(a, b, acc[n], 0, 0, 0);
        }
    }
#pragma unroll
    for (int j = 0; j < 4; ++j) {
        int nrow = nodeBase + wv * 16 + kg * 4 + j;
        if (nrow < NN) {
            float dv = dinv[nrow];
            size_t o = (size_t)nrow * HIDC + r16;
#pragma unroll
            for (int n = 0; n < 4; ++n)
                hp[o + n * 16] = (hf)(acc[n][j] * dv);
        }
    }
}

// ---------------- layer-2 GEMM via MFMA, BN+ReLU fused into the A-frag ----------------
__global__ __launch_bounds__(256) void k_gemm2(
    const hf* __restrict__ agg, const hf* __restrict__ w2t,
    const float* __restrict__ scale, const float* __restrict__ shift,
    const float* __restrict__ dinv, hf* __restrict__ hp) {
    int wv = threadIdx.x >> 6, l = threadIdx.x & 63;
    int r16 = l & 15, kg = l >> 4;
    int nodeBase = blockIdx.x * 64;
    int row = nodeBase + wv * 16 + r16;
    int rowC = row < NN ? row : NN - 1;
    const hf* ar = agg + (size_t)rowC * HIDC + kg * 8;
    f4 acc[4] = {{0.f,0.f,0.f,0.f},{0.f,0.f,0.f,0.f},{0.f,0.f,0.f,0.f},{0.f,0.f,0.f,0.f}};
#pragma unroll
    for (int ks = 0; ks < 2; ++ks) {
        h8 raw = *(const h8*)(ar + ks * 32);
        int ch0 = ks * 32 + kg * 8;
        h8 a;
#pragma unroll
        for (int j = 0; j < 8; ++j) {
            float v = (float)raw[j] * scale[ch0 + j] + shift[ch0 + j];
            a[j] = (hf)fmaxf(v, 0.f);
        }
#pragma unroll
        for (int n = 0; n < 4; ++n) {
            h8 b = *(const h8*)(w2t + (n * 16 + r16) * HIDC + ks * 32 + kg * 8);
            acc[n] = __builtin_amdgcn_mfma_f32_16x16x32_f16(a, b, acc[n], 0, 0, 0);
        }
    }
#pragma unroll
    for (int j = 0; j < 4; ++j) {
        int nrow = nodeBase + wv * 16 + kg * 4 + j;
        if (nrow < NN) {
            float dv = dinv[nrow];
            size_t o = (size_t)nrow * HIDC + r16;
#pragma unroll
            for (int n = 0; n < 4; ++n)
                hp[o + n * 16] = (hf)(acc[n][j] * dv);
        }
    }
}

// ---------------- CSR gather (fp16 table -> fp16 agg, fp32 accumulate) ----------------
__global__ __launch_bounds__(256) void k_gather(
    const int* __restrict__ cursor, const int* __restrict__ srcSorted,
    const float* __restrict__ dinv, const hf* __restrict__ hp,
    hf* __restrict__ agg) {
    int wid = threadIdx.x >> 6, lane = threadIdx.x & 63;
    int n = blockIdx.x * 4 + wid;
    if (n >= NN) return;
    int beg = cursor[n];
    int end = cursor[n + 1];
    float acc = (float)hp[(size_t)n * HIDC + lane];
    for (int base = beg; base < end; base += 64) {
        int m = end - base; if (m > 64) m = 64;
        int si = (base + lane < end) ? srcSorted[base + lane] : 0;
        int j = 0;
        for (; j + 8 <= m; j += 8) {
            int s0 = __shfl(si, j),     s1 = __shfl(si, j + 1);
            int s2 = __shfl(si, j + 2), s3 = __shfl(si, j + 3);
            int s4 = __shfl(si, j + 4), s5 = __shfl(si, j + 5);
            int s6 = __shfl(si, j + 6), s7 = __shfl(si, j + 7);
            float v0 = (float)hp[(size_t)s0 * HIDC + lane];
            float v1 = (float)hp[(size_t)s1 * HIDC + lane];
            float v2 = (float)hp[(size_t)s2 * HIDC + lane];
            float v3 = (float)hp[(size_t)s3 * HIDC + lane];
            float v4 = (float)hp[(size_t)s4 * HIDC + lane];
            float v5 = (float)hp[(size_t)s5 * HIDC + lane];
            float v6 = (float)hp[(size_t)s6 * HIDC + lane];
            float v7 = (float)hp[(size_t)s7 * HIDC + lane];
            acc += ((v0 + v1) + (v2 + v3)) + ((v4 + v5) + (v6 + v7));
        }
        for (; j + 2 <= m; j += 2) {
            int s0 = __shfl(si, j), s1 = __shfl(si, j + 1);
            float v0 = (float)hp[(size_t)s0 * HIDC + lane];
            float v1 = (float)hp[(size_t)s1 * HIDC + lane];
            acc += v0 + v1;
        }
        if (j < m) {
            int s = __shfl(si, j);
            acc += (float)hp[(size_t)s * HIDC + lane];
        }
    }
    agg[(size_t)n * HIDC + lane] = (hf)(dinv[n] * acc);
}

// ---------------- BN statistics (fp16 input, fp32 accumulate) ----------------
__global__ __launch_bounds__(256) void k_stats(
    const hf* __restrict__ agg, float* gsum, float* gsq) {
    __shared__ float ls[256], lq[256];
    int tid = threadIdx.x;
    int c = tid & 63, r = tid >> 6;
    float s = 0.0f, q = 0.0f;
    for (int n = blockIdx.x * 4 + r; n < NN; n += gridDim.x * 4) {
        float v = (float)agg[(size_t)n * HIDC + c];
        s += v; q += v * v;
    }
    ls[tid] = s; lq[tid] = q;
    __syncthreads();
    if (tid < 64) {
        s = ls[tid] + ls[tid + 64] + ls[tid + 128] + ls[tid + 192];
        q = lq[tid] + lq[tid + 64] + lq[tid + 128] + lq[tid + 192];
        atomicAdd(&gsum[c], s);
        atomicAdd(&gsq[c], q);
    }
}

__global__ void k_bnfin(const float* __restrict__ gsum, const float* __restrict__ gsq,
                        const float* __restrict__ g, const float* __restrict__ be,
                        float* scale, float* shift) {
    int c = threadIdx.x;
    if (c < HIDC) {
        float mu = gsum[c] * (1.0f / NN);
        float var = gsq[c] * (1.0f / NN) - mu * mu;
        float inv = rsqrtf(var + EPSV);
        float sc = g[c] * inv;
        scale[c] = sc;
        shift[c] = be[c] - mu * sc;
    }
}

// ---------------- MLP head (fp16 agg input, BN+ReLU fused) ----------------
__global__ __launch_bounds__(256) void k_mlp(
    const hf* __restrict__ agg, const float* __restrict__ scale,
    const float* __restrict__ shift,
    const float* __restrict__ Wm1, const float* __restrict__ bm1,
    const float* __restrict__ Wm2, const float* __restrict__ bm2,
    const float* __restrict__ Wm3, const float* __restrict__ bm3,
    float* __restrict__ out) {
    int n = blockIdx.x * blockDim.x + threadIdx.x;
    if (n >= NN) return;
    float h[HIDC];
#pragma unroll
    for (int cq = 0; cq < 8; ++cq) {
        h8 v8 = *(const h8*)&agg[(size_t)n * HIDC + cq * 8];
#pragma unroll
        for (int j = 0; j < 8; ++j) {
            int c = cq * 8 + j;
            h[c] = fmaxf((float)v8[j] * scale[c] + shift[c], 0.0f);
        }
    }
    float a1[32];
#pragma unroll
    for (int j = 0; j < 32; ++j) {
        float acc = bm1[j];
#pragma unroll
        for (int c = 0; c < HIDC; ++c) acc += h[c] * Wm1[c * 32 + j];
        a1[j] = fmaxf(acc, 0.0f);
    }
    float a2[16];
#pragma unroll
    for (int j = 0; j < 16; ++j) {
        float acc = bm2[j];
#pragma unroll
        for (int c = 0; c < 32; ++c) acc += a1[c] * Wm2[c * 16 + j];
        a2[j] = fmaxf(acc, 0.0f);
    }
    float z = bm3[0];
#pragma unroll
    for (int c = 0; c < 16; ++c) z += a2[c] * Wm3[c];
    out[n] = 1.0f / (1.0f + expf(-z));
}

extern "C" void kernel_launch(void* const* d_in, const int* in_sizes, int n_in,
                              void* d_out, int out_size, void* d_ws, size_t ws_size,
                              hipStream_t stream) {
    const float* x   = (const float*)d_in[0];
    const int*   ei  = (const int*)d_in[1];
    const float* W1  = (const float*)d_in[2];
    // b1 (d_in[3]) cancels in BatchNorm
    const float* g1  = (const float*)d_in[4];
    const float* be1 = (const float*)d_in[5];
    const float* W2  = (const float*)d_in[6];
    // b2 (d_in[7]) cancels in BatchNorm
    const float* g2  = (const float*)d_in[8];
    const float* be2 = (const float*)d_in[9];
    const float* Wm1 = (const float*)d_in[10];
    const float* bm1 = (const float*)d_in[11];
    const float* Wm2 = (const float*)d_in[12];
    const float* bm2 = (const float*)d_in[13];
    const float* Wm3 = (const float*)d_in[14];
    const float* bm3 = (const float*)d_in[15];
    float* out = (float*)d_out;

    const int* srcI = ei;
    const int* dstI = ei + NE;

    int*   bucketTotal = (int*)d_ws;                    // 128
    int*   bucketStart = bucketTotal + 128;             // 128
    int*   bucketCur   = bucketStart + 128;             // 128
    int*   cursor      = bucketCur + 128;               // NN+4
    int*   srcSorted   = cursor + NN + 4;               // NE
    float* dinv        = (float*)(srcSorted + NE);      // NN
    hf*    w1t         = (hf*)(dinv + NN);              // 64*128
    hf*    w2t         = w1t + 64 * 128;                // 64*64
    hf*    hp          = w2t + 64 * 64;                 // NN*64 fp16
    hf*    agg         = hp + (size_t)NN * HIDC;        // NN*64 fp16
    float* stats       = (float*)(agg + (size_t)NN * HIDC);  // 512
    u64*   pairs       = (u64*)hp;                      // aliases hp (dead until gemm1)
    float *sum1 = stats,       *sq1 = stats + 64;
    float *sum2 = stats + 128, *sq2 = stats + 192;
    float *scale1 = stats + 256, *shift1 = stats + 320;
    float *scale2 = stats + 384, *shift2 = stats + 448;

    hipMemsetAsync(bucketTotal, 0, 128 * sizeof(int), stream);
    hipMemsetAsync(stats, 0, 256 * sizeof(float), stream);

    // weight prep + CSR build
    k_prep<<<1, 256, 0, stream>>>(W1, W2, w1t, w2t);
    k_hist<<<(NE + CHUNK - 1) / CHUNK, 256, 0, stream>>>(dstI, bucketTotal);
    k_bscan<<<1, 128, 0, stream>>>(bucketTotal, bucketStart, bucketCur, cursor);
    k_partA<<<(NE + CHUNK - 1) / CHUNK, 256, 0, stream>>>(srcI, dstI, bucketCur, pairs);
    k_partB<<<NBUCK, 256, 0, stream>>>(bucketStart, pairs, srcSorted, cursor, dinv);

    // layer 1
    k_gemm1<<<(NN + 63) / 64, 256, 0, stream>>>(x, w1t, dinv, hp);
    k_gather<<<(NN + 3) / 4, 256, 0, stream>>>(cursor, srcSorted, dinv, hp, agg);
    k_stats<<<512, 256, 0, stream>>>(agg, sum1, sq1);
    k_bnfin<<<1, 64, 0, stream>>>(sum1, sq1, g1, be1, scale1, shift1);

    // layer 2
    k_gemm2<<<(NN + 63) / 64, 256, 0, stream>>>(agg, w2t, scale1, shift1, dinv, hp);
    k_gather<<<(NN + 3) / 4, 256, 0, stream>>>(cursor, srcSorted, dinv, hp, agg);
    k_stats<<<512, 256, 0, stream>>>(agg, sum2, sq2);
    k_bnfin<<<1, 64, 0, stream>>>(sum2, sq2, g2, be2, scale2, shift2);

    // MLP head
    k_mlp<<<(NN + 255) / 256, 256, 0, stream>>>(agg, scale2, shift2,
                                                Wm1, bm1, Wm2, bm2, Wm3, bm3, out);
}